// Round 7
// baseline (326.703 us; speedup 1.0000x reference)
//
#include <hip/hip_runtime.h>

typedef unsigned short u16;
typedef unsigned int u32;
typedef __attribute__((ext_vector_type(8))) short short8v;   // 8 bf16 (4 VGPRs)
typedef __attribute__((ext_vector_type(4))) float f32x4;

// Problem constants
#define NPX   131072      // B*H*W = 32*64*64 pixels
#define CHN   128         // NUM_HIDDENS
#define HWN   4096        // H*W
#define EMB   64
#define NCODE 512

// ws layout (bytes) — total 565,248 (known-safe extent)
#define WS_HIST 0         // 512 * u32
#define WS_LOSS 2048      // 1 * f32
#define WS_CC   4096      // 512 * f32
#define WS_PWT  8192      // 128*64 f32 (pre_w transposed, 32 KB)
#define WS_IDX  40960     // 131072 * u16 (256 KB) -> ends 303104
#define WS_DT   303104    // 512*128 f32 decode table (256 KB) -> ends 565248

// out-region scratch (dead after vq_search; overwritten by vq_decode):
//   zh 32..16777248, zm 16777248..33554464, zl 33554464..50331680 (tiled splits)
//   ch 50855968..50921504, cm ..50987040, cl ..51052576 (tiled cb splits)
// MFMA-tiled layout (u16 units), elem (row r, col d):
//   idx = (r>>4)*1024 + (d>>3)*128 + (r&15)*8 + (d&7)

#define MFMA(a, b, c) __builtin_amdgcn_mfma_f32_16x16x32_bf16((a), (b), (c), 0, 0, 0)

// exact aligned-truncation 3-way split of fp32 into bf16 parts
#define SPLIT3(V, HH, MM, LL) {                          \
  u32 zb_ = __float_as_uint(V);                          \
  HH = zb_ >> 16;                                        \
  float fh_ = __uint_as_float(HH << 16);                 \
  float r1_ = __fsub_rn((V), fh_);                       \
  MM = __float_as_uint(r1_) >> 16;                       \
  float fm_ = __uint_as_float(MM << 16);                 \
  float r2_ = __fsub_rn(r1_, fm_);                       \
  LL = __float_as_uint(r2_) >> 16; }

__device__ __forceinline__ float rec3(u32 hb, u32 mb, u32 lb) {
  return __fadd_rn(__fadd_rn(__uint_as_float(hb), __uint_as_float(mb)),
                   __uint_as_float(lb));
}

// ===================== vq_init =====================
// all blocks: DT[k][o] (fmaf-quad chain, bitwise == old vq_dtab/decode);
// block 0: preW transpose; block 1: cc + tiled codebook splits; block 2:
// zero hist+lossAcc (replaces hipMemsetAsync).
__global__ __launch_bounds__(256) void vq_init(const float* __restrict__ preW,
                                               const float* __restrict__ cb,
                                               const float* __restrict__ postW,
                                               const float* __restrict__ postB,
                                               float* __restrict__ preWT,
                                               float* __restrict__ cc,
                                               u16* __restrict__ ch,
                                               u16* __restrict__ cm,
                                               u16* __restrict__ cl,
                                               float* __restrict__ DT,
                                               u32* __restrict__ wz) {
  int bid = blockIdx.x, tid = threadIdx.x;
  int idx = bid * 256 + tid;
  {   // DT entry (k uniform per 2 waves -> s_load; postW L1-hot gather)
    int k = idx >> 7, o = idx & 127;
    const float* q = cb + k * EMB;
    const float* w = postW + o * EMB;
    float a0 = 0.f, a1 = 0.f, a2 = 0.f, a3 = 0.f;
#pragma unroll
    for (int dd = 0; dd < 64; dd += 4) {
      a0 = fmaf(q[dd + 0], w[dd + 0], a0);
      a1 = fmaf(q[dd + 1], w[dd + 1], a1);
      a2 = fmaf(q[dd + 2], w[dd + 2], a2);
      a3 = fmaf(q[dd + 3], w[dd + 3], a3);
    }
    DT[(size_t)k * 128 + o] = ((a0 + a1) + (a2 + a3)) + postB[o];
  }
  if (bid == 0) {
    for (int i = tid; i < CHN * EMB; i += 256) {
      int c = i >> 6, d = i & 63;
      preWT[i] = preW[d * CHN + c];   // preW is [64][128]
    }
  } else if (bid == 1) {
    for (int t = tid; t < NCODE; t += 256) {
      const float* row = cb + t * EMB;
      float r[8];
#pragma unroll
      for (int j = 0; j < 8; ++j) r[j] = __fmul_rn(row[j], row[j]);
#pragma unroll
      for (int b = 1; b < 8; ++b)
#pragma unroll
        for (int j = 0; j < 8; ++j)
          r[j] = __fadd_rn(r[j], __fmul_rn(row[b * 8 + j], row[b * 8 + j]));
      cc[t] = __fadd_rn(__fadd_rn(__fadd_rn(r[0], r[1]), __fadd_rn(r[2], r[3])),
                        __fadd_rn(__fadd_rn(r[4], r[5]), __fadd_rn(r[6], r[7])));
      int tile = t >> 4, rr = t & 15;
      for (int d = 0; d < EMB; ++d) {
        float v = row[d];
        u32 hh, mm, ll;
        SPLIT3(v, hh, mm, ll)
        size_t ti = (size_t)tile * 1024 + (size_t)(d >> 3) * 128 + rr * 8 + (d & 7);
        ch[ti] = (u16)hh;
        cm[ti] = (u16)mm;
        cl[ti] = (u16)ll;
      }
    }
  } else if (bid == 2) {
    for (int i = tid; i < 513; i += 256) wz[i] = 0;   // hist + lossAcc
  }
}

// ===================== vq_pre =====================
// Identical per-(p,d) arithmetic chain (c ascending, unfused mul+add) to the
// round-6 passing version; d split in QUARTERS (grid 2048 -> 8 blocks/CU).
__global__ __launch_bounds__(256) void vq_pre(const float* __restrict__ A,
                                              const float* __restrict__ preWT,
                                              const float* __restrict__ preB,
                                              u16* __restrict__ zh,
                                              u16* __restrict__ zm,
                                              u16* __restrict__ zl) {
  int bid = blockIdx.x;
  int ph = bid & 511, dh = bid >> 9;     // dh in {0..3}
  int d0 = dh << 4;
  int p = ph * 256 + threadIdx.x;
  int b = p >> 12, hw = p & 4095;
  const float* Ab = A + (size_t)b * CHN * HWN + hw;

  float z[16];
#pragma unroll
  for (int d = 0; d < 16; ++d) z[d] = 0.f;
  for (int c = 0; c < CHN; c += 4) {
    float a0 = Ab[(size_t)(c + 0) * HWN];   // coalesced, 4-deep prefetch
    float a1 = Ab[(size_t)(c + 1) * HWN];
    float a2 = Ab[(size_t)(c + 2) * HWN];
    float a3 = Ab[(size_t)(c + 3) * HWN];
    const float* w = preWT + c * EMB + d0;  // wave-uniform -> s_load
#pragma unroll
    for (int d = 0; d < 16; ++d) z[d] = __fadd_rn(z[d], __fmul_rn(a0, w[d]));
    w += EMB;
#pragma unroll
    for (int d = 0; d < 16; ++d) z[d] = __fadd_rn(z[d], __fmul_rn(a1, w[d]));
    w += EMB;
#pragma unroll
    for (int d = 0; d < 16; ++d) z[d] = __fadd_rn(z[d], __fmul_rn(a2, w[d]));
    w += EMB;
#pragma unroll
    for (int d = 0; d < 16; ++d) z[d] = __fadd_rn(z[d], __fmul_rn(a3, w[d]));
  }
#pragma unroll
  for (int d = 0; d < 16; ++d) z[d] = __fadd_rn(z[d], preB[d0 + d]);

  // exact split + packed stores (8 words per split = two uint4)
  u32 hwd[8], mwd[8], lwd[8];
#pragma unroll
  for (int i = 0; i < 16; ++i) {
    u32 hh, mm, ll;
    SPLIT3(z[i], hh, mm, ll)
    int wdi = i >> 1;
    if ((i & 1) == 0) { hwd[wdi] = hh; mwd[wdi] = mm; lwd[wdi] = ll; }
    else { hwd[wdi] |= hh << 16; mwd[wdi] |= mm << 16; lwd[wdi] |= ll << 16; }
  }
  int tile = p >> 4, rr = p & 15;
  size_t base = (size_t)tile * 1024 + (size_t)(dh * 2) * 128 + rr * 8;
#pragma unroll
  for (int q = 0; q < 2; ++q) {
    size_t off = base + (size_t)q * 128;
    *(uint4*)(zh + off) = make_uint4(hwd[4*q], hwd[4*q+1], hwd[4*q+2], hwd[4*q+3]);
    *(uint4*)(zm + off) = make_uint4(mwd[4*q], mwd[4*q+1], mwd[4*q+2], mwd[4*q+3]);
    *(uint4*)(zl + off) = make_uint4(lwd[4*q], lwd[4*q+1], lwd[4*q+2], lwd[4*q+3]);
  }
}

// ===================== vq_search =====================
// 8-pass split MFMA (identical sequence/order to round-6) + in-kernel exact
// zz (vq_zz's pairwise-8 chain from LDS z) + fused loss/hist/indices
// (vq_combine's exact fmaf chain from LDS z). Grid 1024 (M=128/block).

#define LOADB(T) { size_t ob_ = (size_t)(T) * 1024 + l8;                         \
  Bh0 = *(const short8v*)(ch + ob_); Bh1 = *(const short8v*)(ch + ob_ + 512);    \
  Bm0 = *(const short8v*)(cm + ob_); Bm1 = *(const short8v*)(cm + ob_ + 512);    \
  Bl0 = *(const short8v*)(cl + ob_); Bl1 = *(const short8v*)(cl + ob_ + 512); }

#define COMP(T) {                                                       \
  float ccv_ = scc[((T) << 4) + mcol];                                  \
  _Pragma("unroll")                                                     \
  for (int mt = 0; mt < 2; ++mt) {                                      \
    f32x4 acc = {0.f, 0.f, 0.f, 0.f};                                   \
    acc = MFMA(Ah[mt][0], Bh0, acc); acc = MFMA(Ah[mt][1], Bh1, acc);   \
    acc = MFMA(Am[mt][0], Bh0, acc); acc = MFMA(Am[mt][1], Bh1, acc);   \
    acc = MFMA(Ah[mt][0], Bm0, acc); acc = MFMA(Ah[mt][1], Bm1, acc);   \
    acc = MFMA(Am[mt][0], Bm0, acc); acc = MFMA(Am[mt][1], Bm1, acc);   \
    acc = MFMA(Al[mt][0], Bh0, acc); acc = MFMA(Al[mt][1], Bh1, acc);   \
    acc = MFMA(Ah[mt][0], Bl0, acc); acc = MFMA(Ah[mt][1], Bl1, acc);   \
    acc = MFMA(Al[mt][0], Bm0, acc); acc = MFMA(Al[mt][1], Bm1, acc);   \
    acc = MFMA(Am[mt][0], Bl0, acc); acc = MFMA(Am[mt][1], Bl1, acc);   \
    _Pragma("unroll")                                                   \
    for (int r = 0; r < 4; ++r) {                                       \
      float dist_ = __fadd_rn(__fadd_rn(zzr[mt][r], ccv_), -2.0f * acc[r]); \
      if (dist_ < best[mt][r]) { best[mt][r] = dist_; bidx[mt][r] = ((T) << 4) + mcol; } \
    } } }

__global__ __launch_bounds__(256, 4) void vq_search(const u16* __restrict__ zh,
                                                    const u16* __restrict__ zm,
                                                    const u16* __restrict__ zl,
                                                    const u16* __restrict__ ch,
                                                    const u16* __restrict__ cm,
                                                    const u16* __restrict__ cl,
                                                    const float* __restrict__ cc,
                                                    const float* __restrict__ cb,
                                                    u16* __restrict__ wsIdx,
                                                    float* __restrict__ outIdx,
                                                    float* __restrict__ lossAcc,
                                                    unsigned int* __restrict__ hist) {
  __shared__ float scc[512];
  __shared__ float zs[4][2][16][64];   // [wid][mt][row][d] exact z, 32 KB
  __shared__ u16 kb[4][2][16];
  int tid = threadIdx.x;
  scc[tid] = cc[tid];
  scc[tid + 256] = cc[tid + 256];

  int lane = tid & 63, wid = tid >> 6;
  int Mbase = blockIdx.x * 128 + wid * 32;
  int mcol = lane & 15, g = lane >> 4;
  size_t l8 = (size_t)lane * 8;

  // A fragments: tiled lane-linear loads (coalesced 1KB/instr)
  short8v Ah[2][2], Am[2][2], Al[2][2];
#pragma unroll
  for (int mt = 0; mt < 2; ++mt) {
    size_t tz = (size_t)((Mbase >> 4) + mt) * 1024 + l8;
    Ah[mt][0] = *(const short8v*)(zh + tz); Ah[mt][1] = *(const short8v*)(zh + tz + 512);
    Am[mt][0] = *(const short8v*)(zm + tz); Am[mt][1] = *(const short8v*)(zm + tz + 512);
    Al[mt][0] = *(const short8v*)(zl + tz); Al[mt][1] = *(const short8v*)(zl + tz + 512);
  }
  // exact z into LDS: lane holds row=mcol, d = g*8+e (frag0), 32+g*8+e (frag1)
#pragma unroll
  for (int mt = 0; mt < 2; ++mt)
#pragma unroll
    for (int e = 0; e < 8; ++e) {
      zs[wid][mt][mcol][g * 8 + e] =
          rec3(((u32)(u16)Ah[mt][0][e]) << 16, ((u32)(u16)Am[mt][0][e]) << 16,
               ((u32)(u16)Al[mt][0][e]) << 16);
      zs[wid][mt][mcol][32 + g * 8 + e] =
          rec3(((u32)(u16)Ah[mt][1][e]) << 16, ((u32)(u16)Am[mt][1][e]) << 16,
               ((u32)(u16)Al[mt][1][e]) << 16);
    }
  __syncthreads();

  // zz: exact pairwise-8 chain (bb ascending, then tree) — == old vq_zz
  float zzr[2][4];
#pragma unroll
  for (int mt = 0; mt < 2; ++mt)
#pragma unroll
    for (int r = 0; r < 4; ++r) {
      const float* rowp = &zs[wid][mt][g * 4 + r][0];
      float4 v0 = *(const float4*)(rowp);
      float4 v1 = *(const float4*)(rowp + 4);
      float4 a0, a1;
      a0.x = __fmul_rn(v0.x, v0.x); a0.y = __fmul_rn(v0.y, v0.y);
      a0.z = __fmul_rn(v0.z, v0.z); a0.w = __fmul_rn(v0.w, v0.w);
      a1.x = __fmul_rn(v1.x, v1.x); a1.y = __fmul_rn(v1.y, v1.y);
      a1.z = __fmul_rn(v1.z, v1.z); a1.w = __fmul_rn(v1.w, v1.w);
#pragma unroll
      for (int bb = 1; bb < 8; ++bb) {
        v0 = *(const float4*)(rowp + bb * 8);
        v1 = *(const float4*)(rowp + bb * 8 + 4);
        a0.x = __fadd_rn(a0.x, __fmul_rn(v0.x, v0.x));
        a0.y = __fadd_rn(a0.y, __fmul_rn(v0.y, v0.y));
        a0.z = __fadd_rn(a0.z, __fmul_rn(v0.z, v0.z));
        a0.w = __fadd_rn(a0.w, __fmul_rn(v0.w, v0.w));
        a1.x = __fadd_rn(a1.x, __fmul_rn(v1.x, v1.x));
        a1.y = __fadd_rn(a1.y, __fmul_rn(v1.y, v1.y));
        a1.z = __fadd_rn(a1.z, __fmul_rn(v1.z, v1.z));
        a1.w = __fadd_rn(a1.w, __fmul_rn(v1.w, v1.w));
      }
      zzr[mt][r] = __fadd_rn(
          __fadd_rn(__fadd_rn(a0.x, a0.y), __fadd_rn(a0.z, a0.w)),
          __fadd_rn(__fadd_rn(a1.x, a1.y), __fadd_rn(a1.z, a1.w)));
    }

  float best[2][4];
  int bidx[2][4];
#pragma unroll
  for (int mt = 0; mt < 2; ++mt)
#pragma unroll
    for (int r = 0; r < 4; ++r) { best[mt][r] = 3.4e38f; bidx[mt][r] = 0; }

  short8v Bh0, Bh1, Bm0, Bm1, Bl0, Bl1;
#pragma unroll 2
  for (int t = 0; t < 32; ++t) {
    LOADB(t)
    COMP(t)
  }

  // cross-lane lexicographic (dist, k) min == first-min argmin
#pragma unroll
  for (int mt = 0; mt < 2; ++mt)
#pragma unroll
    for (int r = 0; r < 4; ++r) {
      float v = best[mt][r];
      int ix = bidx[mt][r];
#pragma unroll
      for (int off = 1; off < 16; off <<= 1) {
        float ov = __shfl_xor(v, off, 64);
        int oi = __shfl_xor(ix, off, 64);
        if (ov < v || (ov == v && oi < ix)) { v = ov; ix = oi; }
      }
      if (mcol == 0) {
        int row = Mbase + mt * 16 + g * 4 + r;
        wsIdx[row] = (u16)ix;
        outIdx[row] = (float)ix;
        kb[wid][mt][g * 4 + r] = (u16)ix;
        atomicAdd(&hist[ix], 1u);
      }
    }
  __syncthreads();

  // loss: lanes 0..31 each own one row; exact d-ascending fmaf chain
  // (identical to old vq_combine) against LDS z.
  float ls = 0.f;
  if (lane < 32) {
    int mt = lane >> 4, row = lane & 15;
    int krow = kb[wid][mt][row];
    const float4* q4 = (const float4*)(cb + (krow << 6));
    const float* zrow = &zs[wid][mt][row][0];
#pragma unroll
    for (int bb = 0; bb < 8; ++bb) {
      float4 qa = q4[2 * bb], qb = q4[2 * bb + 1];
      float e;
      e = __fsub_rn(qa.x, zrow[8 * bb + 0]); ls = fmaf(e, e, ls);
      e = __fsub_rn(qa.y, zrow[8 * bb + 1]); ls = fmaf(e, e, ls);
      e = __fsub_rn(qa.z, zrow[8 * bb + 2]); ls = fmaf(e, e, ls);
      e = __fsub_rn(qa.w, zrow[8 * bb + 3]); ls = fmaf(e, e, ls);
      e = __fsub_rn(qb.x, zrow[8 * bb + 4]); ls = fmaf(e, e, ls);
      e = __fsub_rn(qb.y, zrow[8 * bb + 5]); ls = fmaf(e, e, ls);
      e = __fsub_rn(qb.z, zrow[8 * bb + 6]); ls = fmaf(e, e, ls);
      e = __fsub_rn(qb.w, zrow[8 * bb + 7]); ls = fmaf(e, e, ls);
    }
  }
#pragma unroll
  for (int off = 32; off; off >>= 1) ls += __shfl_xor(ls, off, 64);
  if (lane == 0) atomicAdd(lossAcc, ls);
}

// ===================== vq_decode (round-6 verbatim, passed) =====================
__global__ __launch_bounds__(256) void vq_decode(const u16* __restrict__ wsIdx,
                                                 const float* __restrict__ DT,
                                                 float* __restrict__ dec) {
  int p = blockIdx.x * 256 + threadIdx.x;
  int b = p >> 12, hw = p & 4095;
  int k = wsIdx[p];
  const float4* Dk = (const float4*)(DT + (size_t)k * 128);   // L2-hot 512B row
  float* out = dec + (size_t)b * CHN * HWN + hw;
#pragma unroll 4
  for (int oq = 0; oq < 32; ++oq) {
    float4 v = Dk[oq];
    out[(size_t)(4 * oq + 0) * HWN] = v.x;   // coalesced per o
    out[(size_t)(4 * oq + 1) * HWN] = v.y;
    out[(size_t)(4 * oq + 2) * HWN] = v.z;
    out[(size_t)(4 * oq + 3) * HWN] = v.w;
  }
}

// --- finalize: loss scalar + perplexity (unchanged)
__global__ __launch_bounds__(512) void vq_final(const unsigned int* __restrict__ hist,
                                                const float* __restrict__ lossAcc,
                                                float* __restrict__ outLoss,
                                                float* __restrict__ outPerp) {
  __shared__ float sred[8];
  int t = threadIdx.x;
  float c = (float)hist[t];
  float pavg = c * (1.0f / 131072.0f);
  float term = pavg * logf(pavg + 1e-10f);
#pragma unroll
  for (int off = 32; off; off >>= 1) term += __shfl_xor(term, off, 64);
  if ((t & 63) == 0) sred[t >> 6] = term;
  __syncthreads();
  if (t == 0) {
    float s = 0.f;
    for (int i = 0; i < 8; ++i) s += sred[i];
    *outPerp = expf(-s);
    *outLoss = 1.25f * (*lossAcc) * (1.0f / 8388608.0f);
  }
}

extern "C" void kernel_launch(void* const* d_in, const int* in_sizes, int n_in,
                              void* d_out, int out_size, void* d_ws, size_t ws_size,
                              hipStream_t stream) {
  const float* A     = (const float*)d_in[0];
  const float* preW  = (const float*)d_in[1];
  const float* preB  = (const float*)d_in[2];
  const float* cb    = (const float*)d_in[3];
  const float* postW = (const float*)d_in[4];
  const float* postB = (const float*)d_in[5];
  float* out = (float*)d_out;

  char* ws = (char*)d_ws;
  unsigned int* hist = (unsigned int*)(ws + WS_HIST);
  float* lossAcc = (float*)(ws + WS_LOSS);
  float* cc      = (float*)(ws + WS_CC);
  float* preWT   = (float*)(ws + WS_PWT);
  u16* wsIdx     = (u16*)(ws + WS_IDX);
  float* DT      = (float*)(ws + WS_DT);

  // scratch inside the decode-output region (overwritten by vq_decode last)
  char* outc = (char*)d_out;
  u16* zh = (u16*)(outc + 32);
  u16* zm = (u16*)(outc + 16777248);
  u16* zl = (u16*)(outc + 33554464);
  u16* ch = (u16*)(outc + 50855968);
  u16* cm = (u16*)(outc + 50921504);
  u16* cl = (u16*)(outc + 50987040);

  vq_init<<<256, 256, 0, stream>>>(preW, cb, postW, postB, preWT, cc,
                                   ch, cm, cl, DT, (u32*)ws);
  vq_pre<<<2048, 256, 0, stream>>>(A, preWT, preB, zh, zm, zl);
  vq_search<<<1024, 256, 0, stream>>>(zh, zm, zl, ch, cm, cl, cc, cb,
                                      wsIdx, out + 16777218, lossAcc, hist);
  vq_decode<<<512, 256, 0, stream>>>(wsIdx, DT, out + 1);
  vq_final<<<1, 512, 0, stream>>>(hist, lossAcc, out, out + 16777217);
}